// Round 12
// baseline (41.831 us; speedup 1.0000x reference)
//
#include <hip/hip_runtime.h>
#include <hip/hip_bf16.h>

constexpr int B = 4;
constexpr int N = 50000;
constexpr int K = 128;
constexpr int S = 256;
constexpr int NCH = (N + 255) / 256;     // 196 chunks (784 = 98*8 blocks)
constexpr float EPS = 1e-5f;

__device__ __forceinline__ float frcp  (float x) { return __builtin_amdgcn_rcpf(x); }
__device__ __forceinline__ float frsq  (float x) { return __builtin_amdgcn_rsqf(x); }
__device__ __forceinline__ float fsqrt_(float x) { return __builtin_amdgcn_sqrtf(x); }

// ---------------------------------------------------------------------------
// Scalar Jacobi rotation — every operand a NAMED float reference (R11-proven
// spill-proof; array forms, even statically indexed, defeated SROA: R8
// VGPR=52 + scratch).
// ---------------------------------------------------------------------------
__device__ __forceinline__ void jrot(
    float& app, float& apq, float& aqq,
    float& ar1p, float& ar1q,
    float& ar2p, float& ar2q,
    float& v0p, float& v0q, float& v1p, float& v1q,
    float& v2p, float& v2q, float& v3p, float& v3q)
{
  const float theta = 0.5f * (aqq - app) * frcp(apq);
  const float tt = copysignf(
      frcp(fabsf(theta) + fsqrt_(fmaf(theta, theta, 1.f))), theta);
  float c  = frsq(fmaf(tt, tt, 1.f));
  float sn = tt * c;
  const bool tiny = fabsf(apq) < 1e-20f;
  c  = tiny ? 1.f : c;
  sn = tiny ? 0.f : sn;

  const float cc = c * c, ss = sn * sn, cs = c * sn;
  const float app_ = cc * app - 2.f * cs * apq + ss * aqq;
  const float aqq_ = ss * app + 2.f * cs * apq + cc * aqq;
  apq = (cc - ss) * apq + cs * (app - aqq);
  app = app_;  aqq = aqq_;

  float t;
  t = c * ar1p - sn * ar1q;  ar1q = sn * ar1p + c * ar1q;  ar1p = t;
  t = c * ar2p - sn * ar2q;  ar2q = sn * ar2p + c * ar2q;  ar2p = t;

  t = c * v0p - sn * v0q;  v0q = sn * v0p + c * v0q;  v0p = t;
  t = c * v1p - sn * v1q;  v1q = sn * v1p + c * v1q;  v1p = t;
  t = c * v2p - sn * v2q;  v2q = sn * v2p + c * v2q;  v2p = t;
  t = c * v3p - sn * v3q;  v3q = sn * v3p + c * v3q;  v3p = t;
}

// All-scalar Horn-quaternion solve from 16 named moments -> writes 4x4 T.
__device__ __forceinline__ void solve_scalar(
    float m0,  float m1,  float m2,  float m3,
    float m4,  float m5,  float m6,  float m7,
    float m8,  float m9,  float m10, float m11,
    float m12, float m13, float m14, float m15,
    float* To)
{
  const float W   = m0;
  const float inv = frcp(W + EPS);
  const float scx = m1 * inv, scy = m2 * inv, scz = m3 * inv;
  const float tcx = m4 * inv, tcy = m5 * inv, tcz = m6 * inv;
  const float f = 2.f - W * inv;       // H = Σ(w s⊗t)·inv − (2−σ)·sc⊗tc
  const float Sxx = m7  * inv - f * scx * tcx;
  const float Sxy = m8  * inv - f * scx * tcy;
  const float Sxz = m9  * inv - f * scx * tcz;
  const float Syx = m10 * inv - f * scy * tcx;
  const float Syy = m11 * inv - f * scy * tcy;
  const float Syz = m12 * inv - f * scy * tcz;
  const float Szx = m13 * inv - f * scz * tcx;
  const float Szy = m14 * inv - f * scz * tcy;
  const float Szz = m15 * inv - f * scz * tcz;

  float a00 = Sxx + Syy + Szz;
  float a01 = Syz - Szy,  a02 = Szx - Sxz,  a03 = Sxy - Syx;
  float a11 = Sxx - Syy - Szz;
  float a12 = Sxy + Syx,  a13 = Szx + Sxz;
  float a22 = -Sxx + Syy - Szz;
  float a23 = Syz + Szy;
  float a33 = -Sxx - Syy + Szz;

  float v00 = 1.f, v01 = 0.f, v02 = 0.f, v03 = 0.f;
  float v10 = 0.f, v11 = 1.f, v12 = 0.f, v13 = 0.f;
  float v20 = 0.f, v21 = 0.f, v22 = 1.f, v23 = 0.f;
  float v30 = 0.f, v31 = 0.f, v32 = 0.f, v33 = 1.f;

  #pragma unroll 1
  for (int sweep = 0; sweep < 5; ++sweep) {
    jrot(a00, a01, a11, a02, a12, a03, a13,
         v00, v01, v10, v11, v20, v21, v30, v31);
    jrot(a00, a02, a22, a01, a12, a03, a23,
         v00, v02, v10, v12, v20, v22, v30, v32);
    jrot(a00, a03, a33, a01, a13, a02, a23,
         v00, v03, v10, v13, v20, v23, v30, v33);
    jrot(a11, a12, a22, a01, a02, a13, a23,
         v01, v02, v11, v12, v21, v22, v31, v32);
    jrot(a11, a13, a33, a01, a03, a12, a23,
         v01, v03, v11, v13, v21, v23, v31, v33);
    jrot(a22, a23, a33, a02, a03, a12, a13,
         v02, v03, v12, v13, v22, v23, v32, v33);
  }

  const bool b1 = a11 > a00;
  const bool b3 = a33 > a22;
  const bool bb = (b3 ? a33 : a22) > (b1 ? a11 : a00);
  float qw  = bb ? (b3 ? v03 : v02) : (b1 ? v01 : v00);
  float qxv = bb ? (b3 ? v13 : v12) : (b1 ? v11 : v10);
  float qyv = bb ? (b3 ? v23 : v22) : (b1 ? v21 : v20);
  float qzv = bb ? (b3 ? v33 : v32) : (b1 ? v31 : v30);

  const float qn = frsq(qw*qw + qxv*qxv + qyv*qyv + qzv*qzv);
  qw *= qn; qxv *= qn; qyv *= qn; qzv *= qn;

  const float R00 = 1.f - 2.f*(qyv*qyv + qzv*qzv);
  const float R01 = 2.f*(qxv*qyv - qw*qzv);
  const float R02 = 2.f*(qxv*qzv + qw*qyv);
  const float R10 = 2.f*(qxv*qyv + qw*qzv);
  const float R11 = 1.f - 2.f*(qxv*qxv + qzv*qzv);
  const float R12 = 2.f*(qyv*qzv - qw*qxv);
  const float R20 = 2.f*(qxv*qzv - qw*qyv);
  const float R21 = 2.f*(qyv*qzv + qw*qxv);
  const float R22 = 1.f - 2.f*(qxv*qxv + qyv*qyv);

  const float tx = tcx - (R00*scx + R01*scy + R02*scz);
  const float ty = tcy - (R10*scx + R11*scy + R12*scz);
  const float tz = tcz - (R20*scx + R21*scy + R22*scz);

  float4* T4 = (float4*)To;
  T4[0] = make_float4(R00, R01, R02, tx);
  T4[1] = make_float4(R10, R11, R12, ty);
  T4[2] = make_float4(R20, R21, R22, tz);
  T4[3] = make_float4(0.f, 0.f, 0.f, 1.f);
}

// ---------------------------------------------------------------------------
// Kernel 1: gather + moment reduce + FUSED scalar solve (thread-0 tail).
// Block = (b,k), XCD-pinned. The tail is ~500 dependent VALU ops (~0.5µs),
// register-resident (named scalars only), hidden by the co-resident block.
// ---------------------------------------------------------------------------
__global__ __launch_bounds__(256) void gather_solve_kernel(
    const float* __restrict__ src, const float* __restrict__ tgt,
    const float* __restrict__ wts, const int* __restrict__ sel,
    float* __restrict__ T)
{
  const int bid = blockIdx.x;
  const int xcd = bid & 7;
  const int b   = xcd >> 1;                       // batch pinned to XCD pair
  const int k   = ((bid >> 3) << 1) | (xcd & 1);  // bijective over [0,128)
  const int s   = threadIdx.x;

  const int idx = sel[k * S + s];
  const float* ps = src + (size_t)(b * N + idx) * 3;
  const float* pt = tgt + (size_t)(b * N + idx) * 3;
  const float w  = wts[b * N + idx];
  const float px = ps[0], py = ps[1], pz = ps[2];
  const float qx = pt[0], qy = pt[1], qz = pt[2];

  float acc[16];
  acc[0] = w;
  acc[1] = w * px;  acc[2] = w * py;  acc[3] = w * pz;
  acc[4] = w * qx;  acc[5] = w * qy;  acc[6] = w * qz;
  acc[7]  = w * px * qx; acc[8]  = w * px * qy; acc[9]  = w * px * qz;
  acc[10] = w * py * qx; acc[11] = w * py * qy; acc[12] = w * py * qz;
  acc[13] = w * pz * qx; acc[14] = w * pz * qy; acc[15] = w * pz * qz;

  #pragma unroll
  for (int off = 32; off > 0; off >>= 1) {
    #pragma unroll
    for (int i = 0; i < 16; ++i)
      acc[i] += __shfl_down(acc[i], off);
  }

  __shared__ float red[4][16];
  const int lane = threadIdx.x & 63, wv = threadIdx.x >> 6;
  if (lane == 0) {
    #pragma unroll
    for (int i = 0; i < 16; ++i) red[wv][i] = acc[i];
  }
  __syncthreads();

  if (threadIdx.x == 0) {
    // 16 named moments (constant LDS indices -> no private arrays)
    const float m0  = red[0][0]  + red[1][0]  + red[2][0]  + red[3][0];
    const float m1  = red[0][1]  + red[1][1]  + red[2][1]  + red[3][1];
    const float m2  = red[0][2]  + red[1][2]  + red[2][2]  + red[3][2];
    const float m3  = red[0][3]  + red[1][3]  + red[2][3]  + red[3][3];
    const float m4  = red[0][4]  + red[1][4]  + red[2][4]  + red[3][4];
    const float m5  = red[0][5]  + red[1][5]  + red[2][5]  + red[3][5];
    const float m6  = red[0][6]  + red[1][6]  + red[2][6]  + red[3][6];
    const float m7  = red[0][7]  + red[1][7]  + red[2][7]  + red[3][7];
    const float m8  = red[0][8]  + red[1][8]  + red[2][8]  + red[3][8];
    const float m9  = red[0][9]  + red[1][9]  + red[2][9]  + red[3][9];
    const float m10 = red[0][10] + red[1][10] + red[2][10] + red[3][10];
    const float m11 = red[0][11] + red[1][11] + red[2][11] + red[3][11];
    const float m12 = red[0][12] + red[1][12] + red[2][12] + red[3][12];
    const float m13 = red[0][13] + red[1][13] + red[2][13] + red[3][13];
    const float m14 = red[0][14] + red[1][14] + red[2][14] + red[3][14];
    const float m15 = red[0][15] + red[1][15] + red[2][15] + red[3][15];

    solve_scalar(m0, m1, m2, m3, m4, m5, m6, m7,
                 m8, m9, m10, m11, m12, m13, m14, m15,
                 T + (size_t)(b * K + k) * 16);
  }
}

// ---------------------------------------------------------------------------
// Kernel 2: error evaluation (R8 XCD-pinned version, unchanged)
// ---------------------------------------------------------------------------
constexpr int KPT = 4;
constexpr int KG  = K / KPT;      // 32
constexpr int NSL = 256 / KG;     // 8
constexpr int PPS = 256 / NSL;    // 32

__global__ __launch_bounds__(256) void error_kernel(
    const float* __restrict__ src, const float* __restrict__ tgt,
    const float* __restrict__ wts, const float* __restrict__ T,
    float* __restrict__ partial)
{
  __shared__ float4 sp[256];
  __shared__ float4 sq[256];
  __shared__ float  t4[K][12];
  __shared__ float  red[K][NSL + 1];

  const int bid = blockIdx.x;
  const int xcd = bid & 7;
  const int b   = xcd >> 1;
  const int ch  = ((bid >> 3) << 1) | (xcd & 1);
  const int tid = threadIdx.x;
  const int j   = ch * 256 + tid;

  float4 P = make_float4(0.f, 0.f, 0.f, 0.f);
  float4 Q = make_float4(0.f, 0.f, 0.f, 0.f);
  if (j < N) {
    const float* ps = src + (size_t)(b*N + j) * 3;
    const float* pt = tgt + (size_t)(b*N + j) * 3;
    P.x = ps[0]; P.y = ps[1]; P.z = ps[2]; P.w = wts[b*N + j];
    Q.x = pt[0]; Q.y = pt[1]; Q.z = pt[2];
  }
  sp[tid] = P; sq[tid] = Q;

  if (tid < K) {
    const float* tp = T + (size_t)(b*K + tid) * 16;
    #pragma unroll
    for (int c = 0; c < 12; ++c) t4[tid][c] = tp[c];
  }
  __syncthreads();

  const int kg    = tid & (KG - 1);
  const int slice = tid >> 5;

  float R[KPT][12];
  #pragma unroll
  for (int m = 0; m < KPT; ++m) {
    const int k = kg + m * KG;
    #pragma unroll
    for (int c = 0; c < 12; ++c) R[m][c] = t4[k][c];
  }

  float acc[KPT] = {0.f, 0.f, 0.f, 0.f};
  const int base = slice * PPS;
  #pragma unroll 4
  for (int i = 0; i < PPS; ++i) {
    const float4 p = sp[base + i];
    const float4 q = sq[base + i];
    #pragma unroll
    for (int m = 0; m < KPT; ++m) {
      const float dx = fmaf(R[m][0], p.x, fmaf(R[m][1], p.y, fmaf(R[m][2],  p.z, R[m][3])))  - q.x;
      const float dy = fmaf(R[m][4], p.x, fmaf(R[m][5], p.y, fmaf(R[m][6],  p.z, R[m][7])))  - q.y;
      const float dz = fmaf(R[m][8], p.x, fmaf(R[m][9], p.y, fmaf(R[m][10], p.z, R[m][11]))) - q.z;
      const float d2 = fmaf(dx, dx, fmaf(dy, dy, dz*dz));
      acc[m] = fmaf(p.w, fsqrt_(d2), acc[m]);
    }
  }

  #pragma unroll
  for (int m = 0; m < KPT; ++m)
    red[kg + m * KG][slice] = acc[m];
  __syncthreads();

  if (tid < K) {
    float sum = 0.f;
    #pragma unroll
    for (int s2 = 0; s2 < NSL; ++s2) sum += red[tid][s2];
    partial[((size_t)b * NCH + ch) * K + tid] = sum;
  }
}

// ---------------------------------------------------------------------------
// Kernel 3: argmin (unchanged)
// ---------------------------------------------------------------------------
__global__ __launch_bounds__(256) void argmin_kernel(
    const float* __restrict__ partial, const float* __restrict__ T,
    float* __restrict__ out)
{
  const int b   = blockIdx.x;
  const int tid = threadIdx.x;
  const int k   = tid & (K - 1);
  const int h   = tid >> 7;

  float sum = 0.f;
  #pragma unroll 7
  for (int c = h; c < NCH; c += 2)
    sum += partial[((size_t)b * NCH + c) * K + k];

  __shared__ float vals[256];
  __shared__ int   idxs[K];
  vals[tid] = sum;
  __syncthreads();

  if (tid < K) { vals[tid] = vals[tid] + vals[tid + K]; idxs[tid] = tid; }
  __syncthreads();

  for (int off = K / 2; off > 0; off >>= 1) {
    if (tid < off) {
      const float o = vals[tid + off];
      if (o < vals[tid] || (o == vals[tid] && idxs[tid + off] < idxs[tid])) {
        vals[tid] = o; idxs[tid] = idxs[tid + off];
      }
    }
    __syncthreads();
  }

  const int best = idxs[0];
  if (tid < 16) out[(size_t)b * 16 + tid] = T[(size_t)(b * K + best) * 16 + tid];
}

// ---------------------------------------------------------------------------
extern "C" void kernel_launch(void* const* d_in, const int* in_sizes, int n_in,
                              void* d_out, int out_size, void* d_ws, size_t ws_size,
                              hipStream_t stream) {
  const float* src = (const float*)d_in[0];
  const float* tgt = (const float*)d_in[1];
  const float* wts = (const float*)d_in[2];
  const int*   sel = (const int*)d_in[3];

  float* T       = (float*)d_ws;                       // B*K*16 floats
  float* partial = T + (size_t)B * K * 16;             // B*NCH*K floats

  gather_solve_kernel<<<B * K, 256, 0, stream>>>(src, tgt, wts, sel, T);
  error_kernel<<<B * NCH, 256, 0, stream>>>(src, tgt, wts, T, partial);
  argmin_kernel<<<B, 256, 0, stream>>>(partial, T, (float*)d_out);
}

// Round 13
// 37.320 us; speedup vs baseline: 1.1209x; 1.1209x over previous
//
#include <hip/hip_runtime.h>
#include <hip/hip_bf16.h>

constexpr int B = 4;
constexpr int N = 50000;
constexpr int K = 128;
constexpr int S = 256;
constexpr int NCH = (N + 255) / 256;     // 196 chunks (784 = 98*8 blocks)
constexpr float EPS = 1e-5f;

__device__ __forceinline__ float frcp  (float x) { return __builtin_amdgcn_rcpf(x); }
__device__ __forceinline__ float frsq  (float x) { return __builtin_amdgcn_rsqf(x); }
__device__ __forceinline__ float fsqrt_(float x) { return __builtin_amdgcn_sqrtf(x); }

// ---------------------------------------------------------------------------
// Kernel 1: gather + moment reduce. ONE WAVE per (b,k), 4 samples/thread.
// vs R11 (4 waves/block): cross-lane reduce work drops 4x (96 shuffle ops
// per block instead of 384 + LDS round-trip + __syncthreads), sel loads
// drop 4x (one int4), and 28 staged loads/thread maximize MLP. No LDS.
// ---------------------------------------------------------------------------
__global__ __launch_bounds__(64) void gather_sums_kernel(
    const float* __restrict__ src, const float* __restrict__ tgt,
    const float* __restrict__ wts, const int* __restrict__ sel,
    float* __restrict__ sums)
{
  const int bid = blockIdx.x;
  const int xcd = bid & 7;
  const int b   = xcd >> 1;                       // batch pinned to XCD pair
  const int k   = ((bid >> 3) << 1) | (xcd & 1);  // bijective over [0,128)
  const int t   = threadIdx.x;

  const int4 s4 = *((const int4*)(sel + k * S) + t);   // samples 4t..4t+3

  // stage all 4 samples first (28 named floats -> independent loads, max MLP)
  const size_t i0 = (size_t)(b * N + s4.x), i1 = (size_t)(b * N + s4.y);
  const size_t i2 = (size_t)(b * N + s4.z), i3 = (size_t)(b * N + s4.w);
  const float w0 = wts[i0], w1 = wts[i1], w2 = wts[i2], w3 = wts[i3];
  const float p0x = src[i0*3], p0y = src[i0*3+1], p0z = src[i0*3+2];
  const float p1x = src[i1*3], p1y = src[i1*3+1], p1z = src[i1*3+2];
  const float p2x = src[i2*3], p2y = src[i2*3+1], p2z = src[i2*3+2];
  const float p3x = src[i3*3], p3y = src[i3*3+1], p3z = src[i3*3+2];
  const float q0x = tgt[i0*3], q0y = tgt[i0*3+1], q0z = tgt[i0*3+2];
  const float q1x = tgt[i1*3], q1y = tgt[i1*3+1], q1z = tgt[i1*3+2];
  const float q2x = tgt[i2*3], q2y = tgt[i2*3+1], q2z = tgt[i2*3+2];
  const float q3x = tgt[i3*3], q3y = tgt[i3*3+1], q3z = tgt[i3*3+2];

  float acc[16];
  #pragma unroll
  for (int i = 0; i < 16; ++i) acc[i] = 0.f;

#define ACC_ONE(px,py,pz,qx,qy,qz,w)                                   \
  {                                                                    \
    acc[0] += (w);                                                     \
    acc[1] = fmaf((w),(px),acc[1]); acc[2] = fmaf((w),(py),acc[2]);    \
    acc[3] = fmaf((w),(pz),acc[3]);                                    \
    acc[4] = fmaf((w),(qx),acc[4]); acc[5] = fmaf((w),(qy),acc[5]);    \
    acc[6] = fmaf((w),(qz),acc[6]);                                    \
    const float wx = (w)*(px), wy = (w)*(py), wz = (w)*(pz);           \
    acc[7]  = fmaf(wx,(qx),acc[7]);  acc[8]  = fmaf(wx,(qy),acc[8]);   \
    acc[9]  = fmaf(wx,(qz),acc[9]);  acc[10] = fmaf(wy,(qx),acc[10]);  \
    acc[11] = fmaf(wy,(qy),acc[11]); acc[12] = fmaf(wy,(qz),acc[12]);  \
    acc[13] = fmaf(wz,(qx),acc[13]); acc[14] = fmaf(wz,(qy),acc[14]);  \
    acc[15] = fmaf(wz,(qz),acc[15]);                                   \
  }

  ACC_ONE(p0x,p0y,p0z,q0x,q0y,q0z,w0)
  ACC_ONE(p1x,p1y,p1z,q1x,q1y,q1z,w1)
  ACC_ONE(p2x,p2y,p2z,q2x,q2y,q2z,w2)
  ACC_ONE(p3x,p3y,p3z,q3x,q3y,q3z,w3)
#undef ACC_ONE

  // single-wave butterfly reduce (deterministic order)
  #pragma unroll
  for (int off = 32; off > 0; off >>= 1) {
    #pragma unroll
    for (int i = 0; i < 16; ++i)
      acc[i] += __shfl_down(acc[i], off);
  }

  if (t == 0) {
    float* o = sums + (size_t)(b * K + k) * 16;
    #pragma unroll
    for (int i = 0; i < 16; ++i) o[i] = acc[i];   // constant indices only
  }
}

// ---------------------------------------------------------------------------
// Scalar Jacobi rotation — named float references only (R11-proven
// spill-proof; array forms, even statically indexed, spilled: R8 VGPR=52).
// ---------------------------------------------------------------------------
__device__ __forceinline__ void jrot(
    float& app, float& apq, float& aqq,
    float& ar1p, float& ar1q,
    float& ar2p, float& ar2q,
    float& v0p, float& v0q, float& v1p, float& v1q,
    float& v2p, float& v2q, float& v3p, float& v3q)
{
  const float theta = 0.5f * (aqq - app) * frcp(apq);
  const float tt = copysignf(
      frcp(fabsf(theta) + fsqrt_(fmaf(theta, theta, 1.f))), theta);
  float c  = frsq(fmaf(tt, tt, 1.f));
  float sn = tt * c;
  const bool tiny = fabsf(apq) < 1e-20f;
  c  = tiny ? 1.f : c;
  sn = tiny ? 0.f : sn;

  const float cc = c * c, ss = sn * sn, cs = c * sn;
  const float app_ = cc * app - 2.f * cs * apq + ss * aqq;
  const float aqq_ = ss * app + 2.f * cs * apq + cc * aqq;
  apq = (cc - ss) * apq + cs * (app - aqq);
  app = app_;  aqq = aqq_;

  float t;
  t = c * ar1p - sn * ar1q;  ar1q = sn * ar1p + c * ar1q;  ar1p = t;
  t = c * ar2p - sn * ar2q;  ar2q = sn * ar2p + c * ar2q;  ar2p = t;

  t = c * v0p - sn * v0q;  v0q = sn * v0p + c * v0q;  v0p = t;
  t = c * v1p - sn * v1q;  v1q = sn * v1p + c * v1q;  v1p = t;
  t = c * v2p - sn * v2q;  v2q = sn * v2p + c * v2q;  v2p = t;
  t = c * v3p - sn * v3q;  v3q = sn * v3p + c * v3q;  v3p = t;
}

// ---------------------------------------------------------------------------
// Kernel 2: solve. One LANE per (b,k); 8 blocks x 64 threads; all-scalar
// Horn-quaternion Jacobi -> register-resident (R11-proven, 37.2µs config).
// ---------------------------------------------------------------------------
__global__ __launch_bounds__(64) void solve_kernel(
    const float* __restrict__ sums, float* __restrict__ T)
{
  const int bk = blockIdx.x * 64 + threadIdx.x;    // [0, 512)

  const float4* s4 = (const float4*)(sums + (size_t)bk * 16);
  const float4 sA = s4[0], sB = s4[1], sC = s4[2], sD = s4[3];

  const float W   = sA.x;
  const float inv = frcp(W + EPS);
  const float scx = sA.y * inv, scy = sA.z * inv, scz = sA.w * inv;
  const float tcx = sB.x * inv, tcy = sB.y * inv, tcz = sB.z * inv;
  const float f = 2.f - W * inv;       // H = Σ(w s⊗t)·inv − (2−σ)·sc⊗tc
  const float Sxx = sB.w * inv - f * scx * tcx;
  const float Sxy = sC.x * inv - f * scx * tcy;
  const float Sxz = sC.y * inv - f * scx * tcz;
  const float Syx = sC.z * inv - f * scy * tcx;
  const float Syy = sC.w * inv - f * scy * tcy;
  const float Syz = sD.x * inv - f * scy * tcz;
  const float Szx = sD.y * inv - f * scz * tcx;
  const float Szy = sD.z * inv - f * scz * tcy;
  const float Szz = sD.w * inv - f * scz * tcz;

  float a00 = Sxx + Syy + Szz;
  float a01 = Syz - Szy,  a02 = Szx - Sxz,  a03 = Sxy - Syx;
  float a11 = Sxx - Syy - Szz;
  float a12 = Sxy + Syx,  a13 = Szx + Sxz;
  float a22 = -Sxx + Syy - Szz;
  float a23 = Syz + Szy;
  float a33 = -Sxx - Syy + Szz;

  float v00 = 1.f, v01 = 0.f, v02 = 0.f, v03 = 0.f;
  float v10 = 0.f, v11 = 1.f, v12 = 0.f, v13 = 0.f;
  float v20 = 0.f, v21 = 0.f, v22 = 1.f, v23 = 0.f;
  float v30 = 0.f, v31 = 0.f, v32 = 0.f, v33 = 1.f;

  #pragma unroll 1
  for (int sweep = 0; sweep < 5; ++sweep) {
    jrot(a00, a01, a11, a02, a12, a03, a13,
         v00, v01, v10, v11, v20, v21, v30, v31);
    jrot(a00, a02, a22, a01, a12, a03, a23,
         v00, v02, v10, v12, v20, v22, v30, v32);
    jrot(a00, a03, a33, a01, a13, a02, a23,
         v00, v03, v10, v13, v20, v23, v30, v33);
    jrot(a11, a12, a22, a01, a02, a13, a23,
         v01, v02, v11, v12, v21, v22, v31, v32);
    jrot(a11, a13, a33, a01, a03, a12, a23,
         v01, v03, v11, v13, v21, v23, v31, v33);
    jrot(a22, a23, a33, a02, a03, a12, a13,
         v02, v03, v12, v13, v22, v23, v32, v33);
  }

  const bool b1 = a11 > a00;
  const bool b3 = a33 > a22;
  const bool bb = (b3 ? a33 : a22) > (b1 ? a11 : a00);
  float qw  = bb ? (b3 ? v03 : v02) : (b1 ? v01 : v00);
  float qxv = bb ? (b3 ? v13 : v12) : (b1 ? v11 : v10);
  float qyv = bb ? (b3 ? v23 : v22) : (b1 ? v21 : v20);
  float qzv = bb ? (b3 ? v33 : v32) : (b1 ? v31 : v30);

  const float qn = frsq(qw*qw + qxv*qxv + qyv*qyv + qzv*qzv);
  qw *= qn; qxv *= qn; qyv *= qn; qzv *= qn;

  const float R00 = 1.f - 2.f*(qyv*qyv + qzv*qzv);
  const float R01 = 2.f*(qxv*qyv - qw*qzv);
  const float R02 = 2.f*(qxv*qzv + qw*qyv);
  const float R10 = 2.f*(qxv*qyv + qw*qzv);
  const float R11 = 1.f - 2.f*(qxv*qxv + qzv*qzv);
  const float R12 = 2.f*(qyv*qzv - qw*qxv);
  const float R20 = 2.f*(qxv*qzv - qw*qyv);
  const float R21 = 2.f*(qyv*qzv + qw*qxv);
  const float R22 = 1.f - 2.f*(qxv*qxv + qyv*qyv);

  const float tx = tcx - (R00*scx + R01*scy + R02*scz);
  const float ty = tcy - (R10*scx + R11*scy + R12*scz);
  const float tz = tcz - (R20*scx + R21*scy + R22*scz);

  float4* T4 = (float4*)(T + (size_t)bk * 16);
  T4[0] = make_float4(R00, R01, R02, tx);
  T4[1] = make_float4(R10, R11, R12, ty);
  T4[2] = make_float4(R20, R21, R22, tz);
  T4[3] = make_float4(0.f, 0.f, 0.f, 1.f);
}

// ---------------------------------------------------------------------------
// Kernel 3: error evaluation (XCD-pinned, unchanged from R11)
// ---------------------------------------------------------------------------
constexpr int KPT = 4;
constexpr int KG  = K / KPT;      // 32
constexpr int NSL = 256 / KG;     // 8
constexpr int PPS = 256 / NSL;    // 32

__global__ __launch_bounds__(256) void error_kernel(
    const float* __restrict__ src, const float* __restrict__ tgt,
    const float* __restrict__ wts, const float* __restrict__ T,
    float* __restrict__ partial)
{
  __shared__ float4 sp[256];
  __shared__ float4 sq[256];
  __shared__ float  t4[K][12];
  __shared__ float  red[K][NSL + 1];

  const int bid = blockIdx.x;
  const int xcd = bid & 7;
  const int b   = xcd >> 1;
  const int ch  = ((bid >> 3) << 1) | (xcd & 1);
  const int tid = threadIdx.x;
  const int j   = ch * 256 + tid;

  float4 P = make_float4(0.f, 0.f, 0.f, 0.f);
  float4 Q = make_float4(0.f, 0.f, 0.f, 0.f);
  if (j < N) {
    const float* ps = src + (size_t)(b*N + j) * 3;
    const float* pt = tgt + (size_t)(b*N + j) * 3;
    P.x = ps[0]; P.y = ps[1]; P.z = ps[2]; P.w = wts[b*N + j];
    Q.x = pt[0]; Q.y = pt[1]; Q.z = pt[2];
  }
  sp[tid] = P; sq[tid] = Q;

  if (tid < K) {
    const float* tp = T + (size_t)(b*K + tid) * 16;
    #pragma unroll
    for (int c = 0; c < 12; ++c) t4[tid][c] = tp[c];
  }
  __syncthreads();

  const int kg    = tid & (KG - 1);
  const int slice = tid >> 5;

  float R[KPT][12];
  #pragma unroll
  for (int m = 0; m < KPT; ++m) {
    const int k = kg + m * KG;
    #pragma unroll
    for (int c = 0; c < 12; ++c) R[m][c] = t4[k][c];
  }

  float acc[KPT] = {0.f, 0.f, 0.f, 0.f};
  const int base = slice * PPS;
  #pragma unroll 4
  for (int i = 0; i < PPS; ++i) {
    const float4 p = sp[base + i];
    const float4 q = sq[base + i];
    #pragma unroll
    for (int m = 0; m < KPT; ++m) {
      const float dx = fmaf(R[m][0], p.x, fmaf(R[m][1], p.y, fmaf(R[m][2],  p.z, R[m][3])))  - q.x;
      const float dy = fmaf(R[m][4], p.x, fmaf(R[m][5], p.y, fmaf(R[m][6],  p.z, R[m][7])))  - q.y;
      const float dz = fmaf(R[m][8], p.x, fmaf(R[m][9], p.y, fmaf(R[m][10], p.z, R[m][11]))) - q.z;
      const float d2 = fmaf(dx, dx, fmaf(dy, dy, dz*dz));
      acc[m] = fmaf(p.w, fsqrt_(d2), acc[m]);
    }
  }

  #pragma unroll
  for (int m = 0; m < KPT; ++m)
    red[kg + m * KG][slice] = acc[m];
  __syncthreads();

  if (tid < K) {
    float sum = 0.f;
    #pragma unroll
    for (int s2 = 0; s2 < NSL; ++s2) sum += red[tid][s2];
    partial[((size_t)b * NCH + ch) * K + tid] = sum;
  }
}

// ---------------------------------------------------------------------------
// Kernel 4: argmin (unchanged from R11)
// ---------------------------------------------------------------------------
__global__ __launch_bounds__(256) void argmin_kernel(
    const float* __restrict__ partial, const float* __restrict__ T,
    float* __restrict__ out)
{
  const int b   = blockIdx.x;
  const int tid = threadIdx.x;
  const int k   = tid & (K - 1);
  const int h   = tid >> 7;

  float sum = 0.f;
  #pragma unroll 7
  for (int c = h; c < NCH; c += 2)
    sum += partial[((size_t)b * NCH + c) * K + k];

  __shared__ float vals[256];
  __shared__ int   idxs[K];
  vals[tid] = sum;
  __syncthreads();

  if (tid < K) { vals[tid] = vals[tid] + vals[tid + K]; idxs[tid] = tid; }
  __syncthreads();

  for (int off = K / 2; off > 0; off >>= 1) {
    if (tid < off) {
      const float o = vals[tid + off];
      if (o < vals[tid] || (o == vals[tid] && idxs[tid + off] < idxs[tid])) {
        vals[tid] = o; idxs[tid] = idxs[tid + off];
      }
    }
    __syncthreads();
  }

  const int best = idxs[0];
  if (tid < 16) out[(size_t)b * 16 + tid] = T[(size_t)(b * K + best) * 16 + tid];
}

// ---------------------------------------------------------------------------
extern "C" void kernel_launch(void* const* d_in, const int* in_sizes, int n_in,
                              void* d_out, int out_size, void* d_ws, size_t ws_size,
                              hipStream_t stream) {
  const float* src = (const float*)d_in[0];
  const float* tgt = (const float*)d_in[1];
  const float* wts = (const float*)d_in[2];
  const int*   sel = (const int*)d_in[3];

  float* sums    = (float*)d_ws;                       // B*K*16 floats
  float* T       = sums + (size_t)B * K * 16;          // B*K*16 floats
  float* partial = T + (size_t)B * K * 16;             // B*NCH*K floats

  gather_sums_kernel<<<B * K, 64, 0, stream>>>(src, tgt, wts, sel, sums);
  solve_kernel<<<8, 64, 0, stream>>>(sums, T);
  error_kernel<<<B * NCH, 256, 0, stream>>>(src, tgt, wts, T, partial);
  argmin_kernel<<<B, 256, 0, stream>>>(partial, T, (float*)d_out);
}